// Round 17
// baseline (196.770 us; speedup 1.0000x reference)
//
#include <hip/hip_runtime.h>
#include <hip/hip_bf16.h>

#define HWN   4096
#define CIN   256
#define NINTER 128
#define NBATCH 4
#define BN_EPS 1e-5f
#define LOG2E 1.4426950408889634f
#define SMAX  64.0f  // fixed softmax max (base-2 units; row max ~55 worst-case)

typedef __bf16 bf16_t;
typedef __bf16 bf16x8 __attribute__((ext_vector_type(8)));
typedef __bf16 bf16x4 __attribute__((ext_vector_type(4)));
typedef float  f32x4  __attribute__((ext_vector_type(4)));
typedef float  f32x16 __attribute__((ext_vector_type(16)));

__device__ __forceinline__ float fexp2(float x) {
  return __builtin_amdgcn_exp2f(x);
}

__device__ __forceinline__ void split_bf16(float v, bf16_t& h, bf16_t& l) {
  h = (bf16_t)v;
  l = (bf16_t)(v - (float)h);
}

// R16 form: also zeroes the 512-float stat accumulators (block 0).
__global__ __launch_bounds__(256) void convert_weights(
    const float* __restrict__ tw, const float* __restrict__ pw,
    const float* __restrict__ gw, const float* __restrict__ ww,
    bf16_t* __restrict__ out, float* __restrict__ stats) {
  int i = blockIdx.x * 256 + threadIdx.x;  // 131072 total
  if (blockIdx.x == 0) {
    stats[threadIdx.x] = 0.f;
    stats[256 + threadIdx.x] = 0.f;
  }
  float v;
  if (i < 32768)        v = tw[i];
  else if (i < 65536)   v = pw[i - 32768];
  else if (i < 98304)   v = gw[i - 65536];
  else                  v = ww[i - 98304];
  bf16_t h, l;
  split_bf16(v, h, l);
  out[i] = h;
  out[131072 + i] = l;
}

// Fused QKV conv (R13/R16 form: x register-prefetch). n-tile 32, grid (128,4).
__global__ __launch_bounds__(256, 4) void qkv_kernel(
    const float* __restrict__ x, const bf16_t* __restrict__ wbf,
    const float* __restrict__ tb, const float* __restrict__ pb,
    const float* __restrict__ gb,
    bf16_t* __restrict__ Qh, bf16_t* __restrict__ Kh, bf16_t* __restrict__ V) {
  const int ntb  = blockIdx.x;   // 128 tiles of 32 n
  const int b    = blockIdx.y;
  const int tid  = threadIdx.x;
  const int lane = tid & 63;
  const int wv   = tid >> 6;
  const int l31  = lane & 31;
  const int half = lane >> 5;

  __shared__ __align__(16) bf16_t smem[4608];            // 9216 B
  bf16_t (*xTh)[72] = (bf16_t(*)[72])smem;               // [32][72]
  bf16_t (*xTl)[72] = (bf16_t(*)[72])(smem + 2304);      // [32][72]
  bf16_t (*Tr)[136] = (bf16_t(*)[136])smem;              // [32][136] (reuse)

  const bf16_t* Th = wbf;                  // theta hi [128][256]
  const bf16_t* Tl = wbf + 131072;         // theta lo
  const bf16_t* Ph = wbf + 32768;          // phi hi
  const bf16_t* Pl = wbf + 131072 + 32768; // phi lo
  const bf16_t* Gh = wbf + 65536;          // g hi
  const float*  xb = x + (size_t)b * CIN * HWN + ntb * 32;

  f32x16 aq, ak, av;
#pragma unroll
  for (int i = 0; i < 16; i++) { aq[i] = 0.f; ak[i] = 0.f; av[i] = 0.f; }

  float xr[8];                           // staged x tile (fully unrolled idx)
#pragma unroll
  for (int i = 0; i < 8; i++) {
    int idx = tid + i * 256;
    xr[i] = xb[(size_t)(idx >> 5) * HWN + (idx & 31)];
  }

  for (int c0 = 0; c0 < 256; c0 += 64) {
    __syncthreads();
#pragma unroll
    for (int i = 0; i < 8; i++) {        // 2048 elements: 64c x 32n
      int idx = tid + i * 256;
      int cc = idx >> 5;
      int nn = idx & 31;
      bf16_t h, l;
      split_bf16(xr[i], h, l);
      xTh[nn][cc] = h;
      xTl[nn][cc] = l;
    }
    __syncthreads();
    if (c0 + 64 < 256) {                 // prefetch next tile; latency
#pragma unroll                           // hides under the kk loop
      for (int i = 0; i < 8; i++) {
        int idx = tid + i * 256;
        xr[i] = xb[(size_t)(c0 + 64 + (idx >> 5)) * HWN + (idx & 31)];
      }
    }
#pragma unroll
    for (int kk = 0; kk < 64; kk += 16) {
      size_t woff = (size_t)(32 * wv + l31) * 256 + c0 + kk + half * 8;
      bf16x8 th = *(const bf16x8*)(Th + woff);
      bf16x8 tl = *(const bf16x8*)(Tl + woff);
      bf16x8 ph = *(const bf16x8*)(Ph + woff);
      bf16x8 pl = *(const bf16x8*)(Pl + woff);
      bf16x8 gh = *(const bf16x8*)(Gh + woff);
      bf16x8 bh = *(const bf16x8*)(&xTh[l31][kk + half * 8]);
      bf16x8 bl = *(const bf16x8*)(&xTl[l31][kk + half * 8]);
      aq = __builtin_amdgcn_mfma_f32_32x32x16_bf16(th, bh, aq, 0, 0, 0);
      aq = __builtin_amdgcn_mfma_f32_32x32x16_bf16(th, bl, aq, 0, 0, 0);
      aq = __builtin_amdgcn_mfma_f32_32x32x16_bf16(tl, bh, aq, 0, 0, 0);
      ak = __builtin_amdgcn_mfma_f32_32x32x16_bf16(ph, bh, ak, 0, 0, 0);
      ak = __builtin_amdgcn_mfma_f32_32x32x16_bf16(ph, bl, ak, 0, 0, 0);
      ak = __builtin_amdgcn_mfma_f32_32x32x16_bf16(pl, bh, ak, 0, 0, 0);
      av = __builtin_amdgcn_mfma_f32_32x32x16_bf16(gh, bh, av, 0, 0, 0);
    }
  }

  // ---- epilogue: 2 LDS-transpose rounds (Qh, Kh) + direct V store ----
  const int trow = tid >> 3;          // 0..31
  const int tc16 = (tid & 7) * 16;    // 0..112
  bf16_t* qh = Qh + ((size_t)b * HWN + ntb * 32) * NINTER;
  bf16_t* kh = Kh + ((size_t)b * HWN + ntb * 32) * NINTER;

#pragma unroll
  for (int rnd = 0; rnd < 2; rnd++) {
    __syncthreads();
#pragma unroll
    for (int rg = 0; rg < 4; rg++) {
      int och0 = 32 * wv + 8 * rg + 4 * half;
#pragma unroll
      for (int j = 0; j < 4; j++) {
        float v = (rnd == 0) ? (aq[rg * 4 + j] + tb[och0 + j]) * LOG2E
                             : (ak[rg * 4 + j] + pb[och0 + j]);
        Tr[l31][och0 + j] = (bf16_t)v;
      }
    }
    __syncthreads();
    bf16_t* dst = (rnd == 0) ? qh : kh;
    bf16x8 v0 = *(const bf16x8*)(&Tr[trow][tc16]);
    bf16x8 v1 = *(const bf16x8*)(&Tr[trow][tc16 + 8]);
    *(bf16x8*)(dst + (size_t)trow * NINTER + tc16) = v0;
    *(bf16x8*)(dst + (size_t)trow * NINTER + tc16 + 8) = v1;
  }

  const int n = ntb * 32 + l31;
  bf16_t* vd = V + (size_t)b * NINTER * HWN;
#pragma unroll
  for (int r = 0; r < 16; r++) {
    int och = 32 * wv + (r & 3) + 8 * (r >> 2) + 4 * half;
    vd[(size_t)och * HWN + n] = (bf16_t)(av[r] + gb[och]);
  }
}

// Flash attention pass 1. ROUND-17: chunked OP partials replaced by
// DIRECT fp32 atomicAdd accumulation into one 8MB O buffer + 64KB L
// buffer (zeroed by a ~free memset, R16 datum). Mechanism: R9 priced
// OP bytes at ~0.3us/MB; this deletes 24MB of attn writes and 24MB of
// wconv reads. Numerics = fp32 addition reordering only — R10/R11
// proved absmax stays 0.125 under atomic reordering. Epilogue: 72
// scalar atomics/thread, 8.4M total over 2M addresses (4 adds/addr,
// no contention per R11).
template<int NCv>
__global__ __launch_bounds__(512, 1) void attn_kernel(
    const bf16_t* __restrict__ Qh, const bf16_t* __restrict__ Kh,
    const bf16_t* __restrict__ V,
    float* __restrict__ O, float* __restrict__ Lp) {
  constexpr int CH = HWN / NCv;   // keys per chunk (1024)
  constexpr int NT = CH / 64;     // 64-key tiles per block (16)
  const int qt    = blockIdx.x;   // 16 tiles of 256 q
  const int chunk = blockIdx.y;
  const int b     = blockIdx.z;
  const int tid   = threadIdx.x;
  const int lane  = tid & 63;
  const int wv    = tid >> 6;     // 0..7
  const int l15   = lane & 15;
  const int quad  = lane >> 4;
  const int kbase = chunk * CH;

  __shared__ __align__(16) bf16_t Klds[64][136];   // 17408 B
  __shared__ __align__(16) bf16_t Vlds[144][72];   // 20736 B (row 128: ones; 129+: zeros)
  __shared__ __align__(16) bf16_t Plds[8][32][72]; // 36864 B, [wave][q][key]

  const bf16_t* Qhb = Qh + (size_t)b * HWN * NINTER;
  const bf16_t* Khb = Kh + (size_t)b * HWN * NINTER;
  const bf16_t* Vb  = V + (size_t)b * NINTER * HWN;

  if (tid < 144) {                       // ones/zeros rows 128..143 x 72
    int row = 128 + tid / 9;
    int c8 = (tid % 9) * 8;
    bf16x8 v;
#pragma unroll
    for (int j = 0; j < 8; j++) v[j] = (bf16_t)((row == 128) ? 1.0f : 0.0f);
    *(bf16x8*)(&Vlds[row][c8]) = v;
  }

  bf16x8 qf[2][4];
#pragma unroll
  for (int qs = 0; qs < 2; qs++) {
    const int qrow = qt * 256 + wv * 32 + qs * 16 + l15;
#pragma unroll
    for (int kc = 0; kc < 4; kc++)
      qf[qs][kc] = *(const bf16x8*)(Qhb + (size_t)qrow * NINTER + kc * 32 + quad * 8);
  }

  f32x4 o[2][8], ol[2];
#pragma unroll
  for (int qs = 0; qs < 2; qs++) {
#pragma unroll
    for (int dt = 0; dt < 8; dt++)
#pragma unroll
      for (int i = 0; i < 4; i++) o[qs][dt][i] = 0.f;
#pragma unroll
    for (int i = 0; i < 4; i++) ol[qs][i] = 0.f;
  }

  // Per-thread staging slots (512 threads: 2 uint4 for K, 2 for V)
  const int krow = tid >> 4;            // 0..31 (also krow+32)
  const int kc8  = (tid & 15) * 8;      // 0..120
  const int vrow = tid >> 3;            // 0..63 (also vrow+64)
  const int vc8  = (tid & 7) * 8;       // 0..56
  const bf16_t* kgp = Khb + (size_t)(kbase + krow) * NINTER + kc8;
  const bf16_t* vgp = Vb + (size_t)vrow * HWN + kbase + vc8;

  uint4 ka = *(const uint4*)(kgp);                          // tile 0 in flight
  uint4 kb = *(const uint4*)(kgp + (size_t)32 * NINTER);
  uint4 va = *(const uint4*)(vgp);
  uint4 vb = *(const uint4*)(vgp + (size_t)64 * HWN);

  for (int t = 0; t < NT; t++) {
    __syncthreads();                    // all waves done reading tile t-1
    *(uint4*)(&Klds[krow][kc8]) = ka;   // vmcnt drained during prior compute
    *(uint4*)(&Klds[krow + 32][kc8]) = kb;
    *(uint4*)(&Vlds[vrow][vc8]) = va;
    *(uint4*)(&Vlds[vrow + 64][vc8]) = vb;
    __syncthreads();                    // tile t visible

    if (t + 1 < NT) {                   // prefetch tile t+1; stays in flight
      const bf16_t* kn = kgp + (size_t)(t + 1) * 64 * NINTER;
      const bf16_t* vn = vgp + (t + 1) * 64;
      ka = *(const uint4*)(kn);
      kb = *(const uint4*)(kn + (size_t)32 * NINTER);
      va = *(const uint4*)(vn);
      vb = *(const uint4*)(vn + (size_t)64 * HWN);
    }

    // S^T tiles: s[qs][ks], C col = q (l15), row = key (ks*16+quad*4+r)
    f32x4 s[2][4];
#pragma unroll
    for (int qs = 0; qs < 2; qs++)
#pragma unroll
      for (int ks = 0; ks < 4; ks++)
#pragma unroll
        for (int i = 0; i < 4; i++) s[qs][ks][i] = 0.f;
#pragma unroll
    for (int ks = 0; ks < 4; ks++)
#pragma unroll
      for (int kc = 0; kc < 4; kc++) {
        bf16x8 kf = *(const bf16x8*)(&Klds[ks * 16 + l15][kc * 32 + quad * 8]);
        s[0][ks] = __builtin_amdgcn_mfma_f32_16x16x32_bf16(kf, qf[0][kc], s[0][ks], 0, 0, 0);
        s[1][ks] = __builtin_amdgcn_mfma_f32_16x16x32_bf16(kf, qf[1][kc], s[1][ks], 0, 0, 0);
      }

    // fixed-max softmax; contiguous bf16x4 P-write per (qs,ks):
    // P[q = qs*16+l15][key = ks*16 + quad*4 + r]
#pragma unroll
    for (int qs = 0; qs < 2; qs++)
#pragma unroll
      for (int ks = 0; ks < 4; ks++) {
        bf16x4 p4;
#pragma unroll
        for (int r = 0; r < 4; r++)
          p4[r] = (bf16_t)fexp2(s[qs][ks][r] - SMAX);
        *(bf16x4*)(&Plds[wv][qs * 16 + l15][ks * 16 + quad * 4]) = p4;
      }

    // PV over two 32-key halves
#pragma unroll
    for (int kh = 0; kh < 2; kh++) {
      bf16x8 pf0 = *(const bf16x8*)(&Plds[wv][l15][kh * 32 + quad * 8]);
      bf16x8 pf1 = *(const bf16x8*)(&Plds[wv][16 + l15][kh * 32 + quad * 8]);
#pragma unroll
      for (int dt = 0; dt < 8; dt++) {
        bf16x8 vf = *(const bf16x8*)(&Vlds[dt * 16 + l15][kh * 32 + quad * 8]);
        o[0][dt] = __builtin_amdgcn_mfma_f32_16x16x32_bf16(pf0, vf, o[0][dt], 0, 0, 0);
        o[1][dt] = __builtin_amdgcn_mfma_f32_16x16x32_bf16(pf1, vf, o[1][dt], 0, 0, 0);
      }
      bf16x8 vfl = *(const bf16x8*)(&Vlds[128 + l15][kh * 32 + quad * 8]);
      ol[0] = __builtin_amdgcn_mfma_f32_16x16x32_bf16(pf0, vfl, ol[0], 0, 0, 0);
      ol[1] = __builtin_amdgcn_mfma_f32_16x16x32_bf16(pf1, vfl, ol[1], 0, 0, 0);
    }
  }

  // Epilogue: accumulate this chunk's partials via device-scope atomics.
  float* Ob = O + (size_t)b * HWN * NINTER;
  float* Lb = Lp + (size_t)b * HWN;
#pragma unroll
  for (int qs = 0; qs < 2; qs++)
#pragma unroll
    for (int r = 0; r < 4; r++) {
      int n = qt * 256 + wv * 32 + qs * 16 + quad * 4 + r;
#pragma unroll
      for (int dt = 0; dt < 8; dt++)
        atomicAdd(&Ob[(size_t)n * NINTER + dt * 16 + l15], o[qs][dt][r]);
      if (l15 == 0)
        atomicAdd(&Lb[n], ol[qs][r]);
    }
}

// Fused combine + W conv. ROUND-17: O is fully accumulated fp32 (atomic
// path) — single read, no NC loop; Linv from single Lp value.
__global__ __launch_bounds__(256, 4) void wconv_kernel(
    const bf16_t* __restrict__ Wbf, const float* __restrict__ O,
    const float* __restrict__ Lp, const float* __restrict__ Wb,
    bf16_t* __restrict__ WY) {
  const int ntb = blockIdx.x;   // 128 tiles of 32 n
  const int b   = blockIdx.y;
  const int tid = threadIdx.x;
  const int lane = tid & 63;
  const int wv   = tid >> 6;
  const int l31  = lane & 31;
  const int half = lane >> 5;

  __shared__ __align__(16) bf16_t Ylds[32][136];
  __shared__ float Linv[32];

  if (tid < 32) {
    int n = ntb * 32 + tid;
    Linv[tid] = 1.f / Lp[(size_t)b * HWN + n];
  }

  const int nrow = tid >> 3;
  const int dgrp = tid & 7;
  const float* Op = O +
      ((size_t)b * HWN + ntb * 32 + nrow) * NINTER + dgrp * 16;
  float oacc[16];
#pragma unroll
  for (int q = 0; q < 4; q++) {
    f32x4 v = *(const f32x4*)(Op + q * 4);
#pragma unroll
    for (int j = 0; j < 4; j++) oacc[q * 4 + j] = v[j];
  }
  __syncthreads();   // Linv ready
  {
    float inv = Linv[nrow];
    bf16x8 y0, y1;
#pragma unroll
    for (int j = 0; j < 8; j++) {
      y0[j] = (bf16_t)(oacc[j] * inv);
      y1[j] = (bf16_t)(oacc[8 + j] * inv);
    }
    *(bf16x8*)(&Ylds[nrow][dgrp * 16]) = y0;
    *(bf16x8*)(&Ylds[nrow][dgrp * 16 + 8]) = y1;
  }
  __syncthreads();

  const bf16_t* Wh = Wbf + 98304;  // [256][128] hi
  f32x16 acc[2];
#pragma unroll
  for (int c = 0; c < 2; c++)
#pragma unroll
    for (int i = 0; i < 16; i++) acc[c][i] = 0.f;

#pragma unroll
  for (int k0 = 0; k0 < 128; k0 += 16) {
    bf16x8 a0 = *(const bf16x8*)(Wh + (size_t)(wv * 64 + l31) * NINTER + k0 + half * 8);
    bf16x8 a1 = *(const bf16x8*)(Wh + (size_t)(wv * 64 + 32 + l31) * NINTER + k0 + half * 8);
    bf16x8 b0 = *(const bf16x8*)(&Ylds[l31][k0 + half * 8]);
    acc[0] = __builtin_amdgcn_mfma_f32_32x32x16_bf16(a0, b0, acc[0], 0, 0, 0);
    acc[1] = __builtin_amdgcn_mfma_f32_32x32x16_bf16(a1, b0, acc[1], 0, 0, 0);
  }

  bf16_t* dst = WY + (size_t)b * 256 * HWN + ntb * 32;
#pragma unroll
  for (int ct = 0; ct < 2; ct++)
#pragma unroll
    for (int r = 0; r < 16; r++) {
      int co = wv * 64 + ct * 32 + (r & 3) + 8 * (r >> 2) + 4 * half;
      dst[(size_t)co * HWN + l31] = (bf16_t)(acc[ct][r] + Wb[co]);
    }
}

// stats split (c,b) -> 1024 blocks. Each block reads one 8KB row,
// wave+LDS reduce, 2 atomicAdds of raw Sigma/Sigma2. bn finalizes.
__global__ __launch_bounds__(256) void stats_kernel(
    const bf16_t* __restrict__ WY, float* __restrict__ stats) {
  const int c = blockIdx.x;
  const int b = blockIdx.y;
  const int tid = threadIdx.x;
  const bf16_t* p = WY + ((size_t)b * 256 + c) * HWN;
  float s = 0.f, s2 = 0.f;
#pragma unroll
  for (int j = 0; j < 2; j++) {
    bf16x8 v8 = *(const bf16x8*)(p + tid * 16 + j * 8);
#pragma unroll
    for (int k = 0; k < 8; k++) {
      float v = (float)v8[k];
      s += v;
      s2 += v * v;
    }
  }
#pragma unroll
  for (int off = 1; off < 64; off <<= 1) {
    s += __shfl_xor(s, off);
    s2 += __shfl_xor(s2, off);
  }
  __shared__ float red[8];
  int wv = tid >> 6;
  if ((tid & 63) == 0) { red[wv] = s; red[4 + wv] = s2; }
  __syncthreads();
  if (tid == 0) {
    atomicAdd(&stats[c], red[0] + red[1] + red[2] + red[3]);
    atomicAdd(&stats[256 + c], red[4] + red[5] + red[6] + red[7]);
  }
}

__global__ __launch_bounds__(256) void bn_kernel(
    const bf16_t* __restrict__ WY, const float* __restrict__ x,
    const float* __restrict__ stats, const float* __restrict__ gamma,
    const float* __restrict__ beta, float* __restrict__ out) {
  int idx = blockIdx.x * 256 + threadIdx.x;
  int e = idx * 4;
  int c = (e >> 12) & 255;
  bf16x4 w4 = *(const bf16x4*)(WY + e);
  float4 xv = *(const float4*)(x + e);
  float S  = stats[c];
  float S2 = stats[256 + c];
  float mean = S * (1.f / 16384.f);
  float var = S2 * (1.f / 16384.f) - mean * mean;
  float g = gamma[c] * rsqrtf(var + BN_EPS);
  float bb = beta[c];
  float4 o;
  o.x = g * ((float)w4[0] - mean) + bb + xv.x;
  o.y = g * ((float)w4[1] - mean) + bb + xv.y;
  o.z = g * ((float)w4[2] - mean) + bb + xv.z;
  o.w = g * ((float)w4[3] - mean) + bb + xv.w;
  *(float4*)(out + e) = o;
}

extern "C" void kernel_launch(void* const* d_in, const int* in_sizes, int n_in,
                              void* d_out, int out_size, void* d_ws, size_t ws_size,
                              hipStream_t stream) {
  const float* x       = (const float*)d_in[0];
  const float* theta_b = (const float*)d_in[2];
  const float* phi_b   = (const float*)d_in[4];
  const float* g_b     = (const float*)d_in[6];
  const float* W_b     = (const float*)d_in[8];
  const float* bn_g    = (const float*)d_in[9];
  const float* bn_b    = (const float*)d_in[10];
  float* out = (float*)d_out;

  // Workspace: QH 4M | KH 4M | V 4M | O fp32 8M | LP 64K | WY bf16 8M |
  // WBF 512K | ST 2K  (~28.6 MB). O+LP contiguous -> one memset.
  constexpr int NC = 4;
  char* ws = (char*)d_ws;
  bf16_t* Qh  = (bf16_t*)(ws);
  bf16_t* Kh  = (bf16_t*)(ws + 4194304);
  bf16_t* V   = (bf16_t*)(ws + 8388608);
  float*  O   = (float*)(ws + 12582912);              // 8 MiB
  float*  LP  = (float*)(ws + 12582912 + 8388608);    // 64 KiB
  bf16_t* WY  = (bf16_t*)(ws + 12582912 + 8388608 + 65536);
  bf16_t* WBF = (bf16_t*)(ws + 12582912 + 8388608 + 65536 + 8388608);
  float*  ST  = (float*)(ws + 12582912 + 8388608 + 65536 + 8388608 + 524288);

  hipMemsetAsync(O, 0, 8388608 + 65536, stream);   // zero O + LP accumulators
  convert_weights<<<512, 256, 0, stream>>>(
      (const float*)d_in[1], (const float*)d_in[3],
      (const float*)d_in[5], (const float*)d_in[7], WBF, ST);
  qkv_kernel<<<dim3(128, NBATCH), 256, 0, stream>>>(
      x, WBF, theta_b, phi_b, g_b, Qh, Kh, V);
  attn_kernel<NC><<<dim3(16, NC, NBATCH), 512, 0, stream>>>(
      Qh, Kh, V, O, LP);
  wconv_kernel<<<dim3(128, NBATCH), 256, 0, stream>>>(
      WBF, O, LP, W_b, WY);
  stats_kernel<<<dim3(256, NBATCH), 256, 0, stream>>>(WY, ST);
  bn_kernel<<<4096, 256, 0, stream>>>(WY, x, ST, bn_g, bn_b, out);
}

// Round 18
// 173.182 us; speedup vs baseline: 1.1362x; 1.1362x over previous
//
#include <hip/hip_runtime.h>
#include <hip/hip_bf16.h>

#define HWN   4096
#define CIN   256
#define NINTER 128
#define NBATCH 4
#define BN_EPS 1e-5f
#define LOG2E 1.4426950408889634f
#define SMAX  64.0f  // fixed softmax max (base-2 units; row max ~55 worst-case)

typedef __bf16 bf16_t;
typedef __bf16 bf16x8 __attribute__((ext_vector_type(8)));
typedef __bf16 bf16x4 __attribute__((ext_vector_type(4)));
typedef float  f32x4  __attribute__((ext_vector_type(4)));
typedef float  f32x16 __attribute__((ext_vector_type(16)));

__device__ __forceinline__ float fexp2(float x) {
  return __builtin_amdgcn_exp2f(x);
}

__device__ __forceinline__ void split_bf16(float v, bf16_t& h, bf16_t& l) {
  h = (bf16_t)v;
  l = (bf16_t)(v - (float)h);
}

// Also zeroes the 512-float stat accumulators (block 0) — saves the
// separate hipMemsetAsync launch. Stream order guarantees completion
// before stats_kernel runs.
__global__ __launch_bounds__(256) void convert_weights(
    const float* __restrict__ tw, const float* __restrict__ pw,
    const float* __restrict__ gw, const float* __restrict__ ww,
    bf16_t* __restrict__ out, float* __restrict__ stats) {
  int i = blockIdx.x * 256 + threadIdx.x;  // 131072 total
  if (blockIdx.x == 0) {
    stats[threadIdx.x] = 0.f;
    stats[256 + threadIdx.x] = 0.f;
  }
  float v;
  if (i < 32768)        v = tw[i];
  else if (i < 65536)   v = pw[i - 32768];
  else if (i < 98304)   v = gw[i - 65536];
  else                  v = ww[i - 98304];
  bf16_t h, l;
  split_bf16(v, h, l);
  out[i] = h;
  out[131072 + i] = l;
}

// Fused QKV conv. n-tile 32, grid (128, 4).
// x-staging register-prefetch (the R7 attn pattern): the next c0-tile's
// 8 x floats load into registers DURING the kk compute phase instead of
// between the two barriers.
__global__ __launch_bounds__(256, 4) void qkv_kernel(
    const float* __restrict__ x, const bf16_t* __restrict__ wbf,
    const float* __restrict__ tb, const float* __restrict__ pb,
    const float* __restrict__ gb,
    bf16_t* __restrict__ Qh, bf16_t* __restrict__ Kh, bf16_t* __restrict__ V) {
  const int ntb  = blockIdx.x;   // 128 tiles of 32 n
  const int b    = blockIdx.y;
  const int tid  = threadIdx.x;
  const int lane = tid & 63;
  const int wv   = tid >> 6;
  const int l31  = lane & 31;
  const int half = lane >> 5;

  __shared__ __align__(16) bf16_t smem[4608];            // 9216 B
  bf16_t (*xTh)[72] = (bf16_t(*)[72])smem;               // [32][72]
  bf16_t (*xTl)[72] = (bf16_t(*)[72])(smem + 2304);      // [32][72]
  bf16_t (*Tr)[136] = (bf16_t(*)[136])smem;              // [32][136] (reuse)

  const bf16_t* Th = wbf;                  // theta hi [128][256]
  const bf16_t* Tl = wbf + 131072;         // theta lo
  const bf16_t* Ph = wbf + 32768;          // phi hi
  const bf16_t* Pl = wbf + 131072 + 32768; // phi lo
  const bf16_t* Gh = wbf + 65536;          // g hi
  const float*  xb = x + (size_t)b * CIN * HWN + ntb * 32;

  f32x16 aq, ak, av;
#pragma unroll
  for (int i = 0; i < 16; i++) { aq[i] = 0.f; ak[i] = 0.f; av[i] = 0.f; }

  float xr[8];                           // staged x tile (fully unrolled idx)
#pragma unroll
  for (int i = 0; i < 8; i++) {
    int idx = tid + i * 256;
    xr[i] = xb[(size_t)(idx >> 5) * HWN + (idx & 31)];
  }

  for (int c0 = 0; c0 < 256; c0 += 64) {
    __syncthreads();
#pragma unroll
    for (int i = 0; i < 8; i++) {        // 2048 elements: 64c x 32n
      int idx = tid + i * 256;
      int cc = idx >> 5;
      int nn = idx & 31;
      bf16_t h, l;
      split_bf16(xr[i], h, l);
      xTh[nn][cc] = h;
      xTl[nn][cc] = l;
    }
    __syncthreads();
    if (c0 + 64 < 256) {                 // prefetch next tile; latency
#pragma unroll                           // hides under the kk loop
      for (int i = 0; i < 8; i++) {
        int idx = tid + i * 256;
        xr[i] = xb[(size_t)(c0 + 64 + (idx >> 5)) * HWN + (idx & 31)];
      }
    }
#pragma unroll
    for (int kk = 0; kk < 64; kk += 16) {
      size_t woff = (size_t)(32 * wv + l31) * 256 + c0 + kk + half * 8;
      bf16x8 th = *(const bf16x8*)(Th + woff);
      bf16x8 tl = *(const bf16x8*)(Tl + woff);
      bf16x8 ph = *(const bf16x8*)(Ph + woff);
      bf16x8 pl = *(const bf16x8*)(Pl + woff);
      bf16x8 gh = *(const bf16x8*)(Gh + woff);
      bf16x8 bh = *(const bf16x8*)(&xTh[l31][kk + half * 8]);
      bf16x8 bl = *(const bf16x8*)(&xTl[l31][kk + half * 8]);
      aq = __builtin_amdgcn_mfma_f32_32x32x16_bf16(th, bh, aq, 0, 0, 0);
      aq = __builtin_amdgcn_mfma_f32_32x32x16_bf16(th, bl, aq, 0, 0, 0);
      aq = __builtin_amdgcn_mfma_f32_32x32x16_bf16(tl, bh, aq, 0, 0, 0);
      ak = __builtin_amdgcn_mfma_f32_32x32x16_bf16(ph, bh, ak, 0, 0, 0);
      ak = __builtin_amdgcn_mfma_f32_32x32x16_bf16(ph, bl, ak, 0, 0, 0);
      ak = __builtin_amdgcn_mfma_f32_32x32x16_bf16(pl, bh, ak, 0, 0, 0);
      av = __builtin_amdgcn_mfma_f32_32x32x16_bf16(gh, bh, av, 0, 0, 0);
    }
  }

  // ---- epilogue: 2 LDS-transpose rounds (Qh, Kh) + direct V store ----
  const int trow = tid >> 3;          // 0..31
  const int tc16 = (tid & 7) * 16;    // 0..112
  bf16_t* qh = Qh + ((size_t)b * HWN + ntb * 32) * NINTER;
  bf16_t* kh = Kh + ((size_t)b * HWN + ntb * 32) * NINTER;

#pragma unroll
  for (int rnd = 0; rnd < 2; rnd++) {
    __syncthreads();
#pragma unroll
    for (int rg = 0; rg < 4; rg++) {
      int och0 = 32 * wv + 8 * rg + 4 * half;
#pragma unroll
      for (int j = 0; j < 4; j++) {
        float v = (rnd == 0) ? (aq[rg * 4 + j] + tb[och0 + j]) * LOG2E
                             : (ak[rg * 4 + j] + pb[och0 + j]);
        Tr[l31][och0 + j] = (bf16_t)v;
      }
    }
    __syncthreads();
    bf16_t* dst = (rnd == 0) ? qh : kh;
    bf16x8 v0 = *(const bf16x8*)(&Tr[trow][tc16]);
    bf16x8 v1 = *(const bf16x8*)(&Tr[trow][tc16 + 8]);
    *(bf16x8*)(dst + (size_t)trow * NINTER + tc16) = v0;
    *(bf16x8*)(dst + (size_t)trow * NINTER + tc16 + 8) = v1;
  }

  const int n = ntb * 32 + l31;
  bf16_t* vd = V + (size_t)b * NINTER * HWN;
#pragma unroll
  for (int r = 0; r < 16; r++) {
    int och = 32 * wv + (r & 3) + 8 * (r >> 2) + 4 * half;
    vd[(size_t)och * HWN + n] = (bf16_t)(av[r] + gb[och]);
  }
}

// Flash attention pass 1 (measured 49.0-54us across 7 rounds).
// 8 waves/512 thr, 256 q/block, 64-key tiles, register-prefetched
// staging, NC=4, grid (16,4,4) = 256 blocks.
template<int NCv>
__global__ __launch_bounds__(512, 1) void attn_kernel(
    const bf16_t* __restrict__ Qh, const bf16_t* __restrict__ Kh,
    const bf16_t* __restrict__ V,
    float* __restrict__ Opart, float* __restrict__ Lp) {
  constexpr int CH = HWN / NCv;   // keys per chunk (1024)
  constexpr int NT = CH / 64;     // 64-key tiles per block (16)
  const int qt    = blockIdx.x;   // 16 tiles of 256 q
  const int chunk = blockIdx.y;
  const int b     = blockIdx.z;
  const int tid   = threadIdx.x;
  const int lane  = tid & 63;
  const int wv    = tid >> 6;     // 0..7
  const int l15   = lane & 15;
  const int quad  = lane >> 4;
  const int kbase = chunk * CH;

  __shared__ __align__(16) bf16_t Klds[64][136];   // 17408 B
  __shared__ __align__(16) bf16_t Vlds[144][72];   // 20736 B (row 128: ones; 129+: zeros)
  __shared__ __align__(16) bf16_t Plds[8][32][72]; // 36864 B, [wave][q][key]

  const bf16_t* Qhb = Qh + (size_t)b * HWN * NINTER;
  const bf16_t* Khb = Kh + (size_t)b * HWN * NINTER;
  const bf16_t* Vb  = V + (size_t)b * NINTER * HWN;

  if (tid < 144) {                       // ones/zeros rows 128..143 x 72
    int row = 128 + tid / 9;
    int c8 = (tid % 9) * 8;
    bf16x8 v;
#pragma unroll
    for (int j = 0; j < 8; j++) v[j] = (bf16_t)((row == 128) ? 1.0f : 0.0f);
    *(bf16x8*)(&Vlds[row][c8]) = v;
  }

  bf16x8 qf[2][4];
#pragma unroll
  for (int qs = 0; qs < 2; qs++) {
    const int qrow = qt * 256 + wv * 32 + qs * 16 + l15;
#pragma unroll
    for (int kc = 0; kc < 4; kc++)
      qf[qs][kc] = *(const bf16x8*)(Qhb + (size_t)qrow * NINTER + kc * 32 + quad * 8);
  }

  f32x4 o[2][8], ol[2];
#pragma unroll
  for (int qs = 0; qs < 2; qs++) {
#pragma unroll
    for (int dt = 0; dt < 8; dt++)
#pragma unroll
      for (int i = 0; i < 4; i++) o[qs][dt][i] = 0.f;
#pragma unroll
    for (int i = 0; i < 4; i++) ol[qs][i] = 0.f;
  }

  // Per-thread staging slots (512 threads: 2 uint4 for K, 2 for V)
  const int krow = tid >> 4;            // 0..31 (also krow+32)
  const int kc8  = (tid & 15) * 8;      // 0..120
  const int vrow = tid >> 3;            // 0..63 (also vrow+64)
  const int vc8  = (tid & 7) * 8;       // 0..56
  const bf16_t* kgp = Khb + (size_t)(kbase + krow) * NINTER + kc8;
  const bf16_t* vgp = Vb + (size_t)vrow * HWN + kbase + vc8;

  uint4 ka = *(const uint4*)(kgp);                          // tile 0 in flight
  uint4 kb = *(const uint4*)(kgp + (size_t)32 * NINTER);
  uint4 va = *(const uint4*)(vgp);
  uint4 vb = *(const uint4*)(vgp + (size_t)64 * HWN);

  for (int t = 0; t < NT; t++) {
    __syncthreads();                    // all waves done reading tile t-1
    *(uint4*)(&Klds[krow][kc8]) = ka;   // vmcnt drained during prior compute
    *(uint4*)(&Klds[krow + 32][kc8]) = kb;
    *(uint4*)(&Vlds[vrow][vc8]) = va;
    *(uint4*)(&Vlds[vrow + 64][vc8]) = vb;
    __syncthreads();                    // tile t visible

    if (t + 1 < NT) {                   // prefetch tile t+1; stays in flight
      const bf16_t* kn = kgp + (size_t)(t + 1) * 64 * NINTER;
      const bf16_t* vn = vgp + (t + 1) * 64;
      ka = *(const uint4*)(kn);
      kb = *(const uint4*)(kn + (size_t)32 * NINTER);
      va = *(const uint4*)(vn);
      vb = *(const uint4*)(vn + (size_t)64 * HWN);
    }

    // S^T tiles: s[qs][ks], C col = q (l15), row = key (ks*16+quad*4+r)
    f32x4 s[2][4];
#pragma unroll
    for (int qs = 0; qs < 2; qs++)
#pragma unroll
      for (int ks = 0; ks < 4; ks++)
#pragma unroll
        for (int i = 0; i < 4; i++) s[qs][ks][i] = 0.f;
#pragma unroll
    for (int ks = 0; ks < 4; ks++)
#pragma unroll
      for (int kc = 0; kc < 4; kc++) {
        bf16x8 kf = *(const bf16x8*)(&Klds[ks * 16 + l15][kc * 32 + quad * 8]);
        s[0][ks] = __builtin_amdgcn_mfma_f32_16x16x32_bf16(kf, qf[0][kc], s[0][ks], 0, 0, 0);
        s[1][ks] = __builtin_amdgcn_mfma_f32_16x16x32_bf16(kf, qf[1][kc], s[1][ks], 0, 0, 0);
      }

    // fixed-max softmax; contiguous bf16x4 P-write per (qs,ks):
    // P[q = qs*16+l15][key = ks*16 + quad*4 + r]
#pragma unroll
    for (int qs = 0; qs < 2; qs++)
#pragma unroll
      for (int ks = 0; ks < 4; ks++) {
        bf16x4 p4;
#pragma unroll
        for (int r = 0; r < 4; r++)
          p4[r] = (bf16_t)fexp2(s[qs][ks][r] - SMAX);
        *(bf16x4*)(&Plds[wv][qs * 16 + l15][ks * 16 + quad * 4]) = p4;
      }

    // PV over two 32-key halves
#pragma unroll
    for (int kh = 0; kh < 2; kh++) {
      bf16x8 pf0 = *(const bf16x8*)(&Plds[wv][l15][kh * 32 + quad * 8]);
      bf16x8 pf1 = *(const bf16x8*)(&Plds[wv][16 + l15][kh * 32 + quad * 8]);
#pragma unroll
      for (int dt = 0; dt < 8; dt++) {
        bf16x8 vf = *(const bf16x8*)(&Vlds[dt * 16 + l15][kh * 32 + quad * 8]);
        o[0][dt] = __builtin_amdgcn_mfma_f32_16x16x32_bf16(pf0, vf, o[0][dt], 0, 0, 0);
        o[1][dt] = __builtin_amdgcn_mfma_f32_16x16x32_bf16(pf1, vf, o[1][dt], 0, 0, 0);
      }
      bf16x8 vfl = *(const bf16x8*)(&Vlds[128 + l15][kh * 32 + quad * 8]);
      ol[0] = __builtin_amdgcn_mfma_f32_16x16x32_bf16(pf0, vfl, ol[0], 0, 0, 0);
      ol[1] = __builtin_amdgcn_mfma_f32_16x16x32_bf16(pf1, vfl, ol[1], 0, 0, 0);
    }
  }

  float* Ob = Opart + ((size_t)(b * NCv + chunk) * HWN) * NINTER;
#pragma unroll
  for (int qs = 0; qs < 2; qs++)
#pragma unroll
    for (int r = 0; r < 4; r++) {
      int n = qt * 256 + wv * 32 + qs * 16 + quad * 4 + r;
#pragma unroll
      for (int dt = 0; dt < 8; dt++)
        Ob[(size_t)n * NINTER + dt * 16 + l15] = o[qs][dt][r];
      if (l15 == 0)
        Lp[(size_t)(b * NCv + chunk) * HWN + n] = ol[qs][r];
    }
}

// Fused combine + W conv (chunked-OP path — R17 proved the atomic
// alternative costs +22us in RMW throughput).
template<int NCv>
__global__ __launch_bounds__(256, 4) void wconv_kernel(
    const bf16_t* __restrict__ Wbf, const float* __restrict__ Opart,
    const float* __restrict__ Lp, const float* __restrict__ Wb,
    bf16_t* __restrict__ WY) {
  const int ntb = blockIdx.x;   // 128 tiles of 32 n
  const int b   = blockIdx.y;
  const int tid = threadIdx.x;
  const int lane = tid & 63;
  const int wv   = tid >> 6;
  const int l31  = lane & 31;
  const int half = lane >> 5;

  __shared__ __align__(16) bf16_t Ylds[32][136];
  __shared__ float Linv[32];

  if (tid < 32) {
    int n = ntb * 32 + tid;
    float ls = 0.f;
#pragma unroll
    for (int c = 0; c < NCv; c++) ls += Lp[(size_t)(b * NCv + c) * HWN + n];
    Linv[tid] = 1.f / ls;
  }

  const int nrow = tid >> 3;
  const int dgrp = tid & 7;
  float oacc[16];
#pragma unroll
  for (int j = 0; j < 16; j++) oacc[j] = 0.f;
#pragma unroll
  for (int c = 0; c < NCv; c++) {
    const float* Op = Opart +
        ((size_t)(b * NCv + c) * HWN + ntb * 32 + nrow) * NINTER + dgrp * 16;
#pragma unroll
    for (int q = 0; q < 4; q++) {
      f32x4 v = *(const f32x4*)(Op + q * 4);
#pragma unroll
      for (int j = 0; j < 4; j++) oacc[q * 4 + j] += v[j];
    }
  }
  __syncthreads();   // Linv ready
  {
    float inv = Linv[nrow];
    bf16x8 y0, y1;
#pragma unroll
    for (int j = 0; j < 8; j++) {
      y0[j] = (bf16_t)(oacc[j] * inv);
      y1[j] = (bf16_t)(oacc[8 + j] * inv);
    }
    *(bf16x8*)(&Ylds[nrow][dgrp * 16]) = y0;
    *(bf16x8*)(&Ylds[nrow][dgrp * 16 + 8]) = y1;
  }
  __syncthreads();

  const bf16_t* Wh = Wbf + 98304;  // [256][128] hi
  f32x16 acc[2];
#pragma unroll
  for (int c = 0; c < 2; c++)
#pragma unroll
    for (int i = 0; i < 16; i++) acc[c][i] = 0.f;

#pragma unroll
  for (int k0 = 0; k0 < 128; k0 += 16) {
    bf16x8 a0 = *(const bf16x8*)(Wh + (size_t)(wv * 64 + l31) * NINTER + k0 + half * 8);
    bf16x8 a1 = *(const bf16x8*)(Wh + (size_t)(wv * 64 + 32 + l31) * NINTER + k0 + half * 8);
    bf16x8 b0 = *(const bf16x8*)(&Ylds[l31][k0 + half * 8]);
    acc[0] = __builtin_amdgcn_mfma_f32_32x32x16_bf16(a0, b0, acc[0], 0, 0, 0);
    acc[1] = __builtin_amdgcn_mfma_f32_32x32x16_bf16(a1, b0, acc[1], 0, 0, 0);
  }

  bf16_t* dst = WY + (size_t)b * 256 * HWN + ntb * 32;
#pragma unroll
  for (int ct = 0; ct < 2; ct++)
#pragma unroll
    for (int r = 0; r < 16; r++) {
      int co = wv * 64 + ct * 32 + (r & 3) + 8 * (r >> 2) + 4 * half;
      dst[(size_t)co * HWN + l31] = (bf16_t)(acc[ct][r] + Wb[co]);
    }
}

// stats split (c,b) -> 1024 blocks. Each block reads one 8KB row,
// wave+LDS reduce, 2 atomicAdds of raw Sigma/Sigma2. bn finalizes.
__global__ __launch_bounds__(256) void stats_kernel(
    const bf16_t* __restrict__ WY, float* __restrict__ stats) {
  const int c = blockIdx.x;
  const int b = blockIdx.y;
  const int tid = threadIdx.x;
  const bf16_t* p = WY + ((size_t)b * 256 + c) * HWN;
  float s = 0.f, s2 = 0.f;
#pragma unroll
  for (int j = 0; j < 2; j++) {
    bf16x8 v8 = *(const bf16x8*)(p + tid * 16 + j * 8);
#pragma unroll
    for (int k = 0; k < 8; k++) {
      float v = (float)v8[k];
      s += v;
      s2 += v * v;
    }
  }
#pragma unroll
  for (int off = 1; off < 64; off <<= 1) {
    s += __shfl_xor(s, off);
    s2 += __shfl_xor(s2, off);
  }
  __shared__ float red[8];
  int wv = tid >> 6;
  if ((tid & 63) == 0) { red[wv] = s; red[4 + wv] = s2; }
  __syncthreads();
  if (tid == 0) {
    atomicAdd(&stats[c], red[0] + red[1] + red[2] + red[3]);
    atomicAdd(&stats[256 + c], red[4] + red[5] + red[6] + red[7]);
  }
}

__global__ __launch_bounds__(256) void bn_kernel(
    const bf16_t* __restrict__ WY, const float* __restrict__ x,
    const float* __restrict__ stats, const float* __restrict__ gamma,
    const float* __restrict__ beta, float* __restrict__ out) {
  int idx = blockIdx.x * 256 + threadIdx.x;
  int e = idx * 4;
  int c = (e >> 12) & 255;
  bf16x4 w4 = *(const bf16x4*)(WY + e);
  float4 xv = *(const float4*)(x + e);
  float S  = stats[c];
  float S2 = stats[256 + c];
  float mean = S * (1.f / 16384.f);
  float var = S2 * (1.f / 16384.f) - mean * mean;
  float g = gamma[c] * rsqrtf(var + BN_EPS);
  float bb = beta[c];
  float4 o;
  o.x = g * ((float)w4[0] - mean) + bb + xv.x;
  o.y = g * ((float)w4[1] - mean) + bb + xv.y;
  o.z = g * ((float)w4[2] - mean) + bb + xv.z;
  o.w = g * ((float)w4[3] - mean) + bb + xv.w;
  *(float4*)(out + e) = o;
}

extern "C" void kernel_launch(void* const* d_in, const int* in_sizes, int n_in,
                              void* d_out, int out_size, void* d_ws, size_t ws_size,
                              hipStream_t stream) {
  const float* x       = (const float*)d_in[0];
  const float* theta_b = (const float*)d_in[2];
  const float* phi_b   = (const float*)d_in[4];
  const float* g_b     = (const float*)d_in[6];
  const float* W_b     = (const float*)d_in[8];
  const float* bn_g    = (const float*)d_in[9];
  const float* bn_b    = (const float*)d_in[10];
  float* out = (float*)d_out;

  // Workspace (NC=4): QH 4M | KH 4M | V 4M | OP fp32 32M | WY bf16 8M |
  // LP 256K | WBF 512K | ST 2K  (~59.5 MB, round-0 layout)
  constexpr int NC = 4;
  const size_t opb = (size_t)NC * HWN * NINTER * NBATCH * 4;  // OP bytes
  const size_t lpb = (size_t)NC * HWN * NBATCH * 4;           // LP bytes

  char* ws = (char*)d_ws;
  bf16_t* Qh  = (bf16_t*)(ws);
  bf16_t* Kh  = (bf16_t*)(ws + 4194304);
  bf16_t* V   = (bf16_t*)(ws + 8388608);
  float*  OP  = (float*)(ws + 12582912);
  bf16_t* WY  = (bf16_t*)(ws + 12582912 + opb);
  float*  LP  = (float*)(ws + 12582912 + opb + 8388608);
  bf16_t* WBF = (bf16_t*)(ws + 12582912 + opb + 8388608 + lpb);
  float*  ST  = (float*)(ws + 12582912 + opb + 8388608 + lpb + 524288);

  convert_weights<<<512, 256, 0, stream>>>(
      (const float*)d_in[1], (const float*)d_in[3],
      (const float*)d_in[5], (const float*)d_in[7], WBF, ST);
  qkv_kernel<<<dim3(128, NBATCH), 256, 0, stream>>>(
      x, WBF, theta_b, phi_b, g_b, Qh, Kh, V);
  attn_kernel<NC><<<dim3(16, NC, NBATCH), 512, 0, stream>>>(
      Qh, Kh, V, OP, LP);
  wconv_kernel<NC><<<dim3(128, NBATCH), 256, 0, stream>>>(
      WBF, OP, LP, W_b, WY);
  stats_kernel<<<dim3(256, NBATCH), 256, 0, stream>>>(WY, ST);
  bn_kernel<<<4096, 256, 0, stream>>>(WY, x, ST, bn_g, bn_b, out);
}